// Round 7
// baseline (146.710 us; speedup 1.0000x reference)
//
#include <hip/hip_runtime.h>
#include <hip/hip_bf16.h>
#include <hip/hip_fp16.h>

// Sparse gather-FFN, DS-pipe bound. Verified model: per CU, 8192 wave
// ds_read_b128 x 12cyc = 41us issue floor + conflicts/256/2.4GHz.
// R15 (sort idx&7 + spaced-2 rot, RPB=16 shell): 1.494e7 conf, main 67us.
// R16 per-LANE +1 replica @RPB=8: weak (-11%) + shell overhead -> 83.5us.
// R17 octet unit-permutation: NULL (can't change demand by permuting).
// R18 layer-0 VMEM offload + &15 sort: conflicts 1.306e7 = EXACTLY
// 7/8 x 1.494e7 -> &15 sort contributed ZERO (32-bank model confirmed,
// ordering exhausted at the demand floor) and VMEM gathers are 2.5-3x
// slower per instr than DS (main 73.2us, +9 net). Both levers refuted.
// R20: octet-coordinated 2-choice replication on the R15 shell.
// Replicate features f<639 (inputs + layer-0/1 acts = 68% of gathers,
// uniform-index math) at +1 bank group: A1 @61456, B1 @71696 (+20KB ->
// exactly 80KB LDS, still 2 blocks/CU of 160KB). Prepass knows each
// phase-octet (units 8o..8o+7): ring-transport s[g]=c+prefix(D[g]-16)
// clamped to choosable counts flattens octet demand D[g]->16, shifts are
// allocated to units, then the verified counting-sort + spaced-2
// rotation runs on FINAL groups. Main kernel: dup-writes for f<639,
// B-offset = o + (o>=A1BASE ? 10240 : 30720) (2 VALU, hidden).
// Predicted: conflicts 1.306e7 -> 4-7e6, main -> 53-58us.

#define NB   32768
#define NIN  128
#define NL   8
#define NW   256
#define NK   16
#define RPB  16                       // rows per block = 2 octets x 8
#define STORED (NIN + (NL - 1) * NW)  // 1920 features per group
#define NPARAM (NL * NW * NK)         // 32768 (l,u,k) entries
#define NREP   639                    // replicated features (f < NREP)
#define A1BASE 61456                  // replica A: group (f+1)&7
#define B1BASE 71696                  // replica B: group (f+1)&7
#define D0OFF  30720                  // copy0 A->B delta
#define D1OFF  10240                  // copy1 A->B delta
#define LDSBYTES 81920                // exactly 80KB -> 2 blocks/CU

typedef __fp16 fp16v2 __attribute__((ext_vector_type(2)));
typedef unsigned long long u64;

__device__ __forceinline__ unsigned pk16(float a, float b) {
    fp16v2 p = __builtin_amdgcn_cvt_pkrtz(a, b);   // v_cvt_pkrtz_f16_f32
    return __builtin_bit_cast(unsigned, p);
}

__device__ __forceinline__ __half2 as_h2(unsigned u) {
    return __builtin_bit_cast(__half2, u);
}

__device__ __forceinline__ float fast_sigmoid(float x) {
    return __builtin_amdgcn_rcpf(1.0f + __expf(-x));
}

// 8 row-MACs from one 16B packed-f16 word: 4x v_pk_fma_f16
__device__ __forceinline__ void fma_feat(__half2 acc[4], __half2 w2, uint4 p) {
    acc[0] = __hfma2(as_h2(p.x), w2, acc[0]);
    acc[1] = __hfma2(as_h2(p.y), w2, acc[1]);
    acc[2] = __hfma2(as_h2(p.z), w2, acc[2]);
    acc[3] = __hfma2(as_h2(p.w), w2, acc[3]);
}

template <bool PRE>
__global__ __launch_bounds__(256, 2)
void ffn_gather_kernel(const float* __restrict__ inputs,
                       const float* __restrict__ weights,
                       const float* __restrict__ biases,
                       const int*   __restrict__ edge_idx,
                       const int*   __restrict__ idxb,   // absolute A byte offs
                       const unsigned* __restrict__ wpk, // packed (w,w) f16
                       float* __restrict__ out)
{
    __shared__ __align__(16) char vals[LDSBYTES];

    const int t = threadIdx.x;                       // 0..255, unit id
    const long long row0 = (long long)blockIdx.x * RPB;

    // ---- stage 128 input features x 16 rows: t<128 -> A, t>=128 -> B ----
    // inputs are replicated (f < 128 < NREP): write copy0 and copy1.
    {
        const int f = t & 127;
        const long long r0 = row0 + ((t >> 7) << 3);   // +0 (A) or +8 (B)
        float v[8];
        #pragma unroll
        for (int r = 0; r < 8; ++r) v[r] = inputs[(r0 + r) * NIN + f];
        uint4 p;
        p.x = pk16(v[0], v[1]);
        p.y = pk16(v[2], v[3]);
        p.z = pk16(v[4], v[5]);
        p.w = pk16(v[6], v[7]);
        if (t < NIN) {
            *(uint4*)(vals + f * 16)           = p;   // A copy0
            *(uint4*)(vals + A1BASE + f * 16)  = p;   // A copy1 (+1 group)
        } else {
            *(uint4*)(vals + D0OFF + f * 16)   = p;   // B copy0
            *(uint4*)(vals + B1BASE + f * 16)  = p;   // B copy1 (+1 group)
        }
    }
    __syncthreads();

    // ---- layers ----
    #pragma unroll
    for (int l = 0; l < NL; ++l) {
        const int base = (l * NW + t) * NK;

        const float b = biases[l * NW + t];
        __half2 accA[4], accB[4];
        const __half2 bb = __float2half2_rn(b);
        #pragma unroll
        for (int j = 0; j < 4; ++j) { accA[j] = bb; accB[j] = bb; }

        #pragma unroll
        for (int kk = 0; kk < NK / 4; ++kk) {
            int4 o4;          // absolute A offsets (copy0 or copy1)
            __half2 w0, w1, w2, w3;
            if (PRE) {
                o4 = ((const int4*)(idxb + base))[kk];
                uint4 wp = ((const uint4*)(wpk + base))[kk];
                w0 = as_h2(wp.x); w1 = as_h2(wp.y);
                w2 = as_h2(wp.z); w3 = as_h2(wp.w);
            } else {
                int4 i4 = ((const int4*)(edge_idx + base))[kk];
                o4.x = i4.x << 4; o4.y = i4.y << 4;   // copy0 only
                o4.z = i4.z << 4; o4.w = i4.w << 4;
                float4 w4 = ((const float4*)(weights + base))[kk];
                w0 = __float2half2_rn(w4.x);
                w1 = __float2half2_rn(w4.y);
                w2 = __float2half2_rn(w4.z);
                w3 = __float2half2_rn(w4.w);
            }
            // B address: copy0 sits +30720, copy1 sits +10240 from A addr
            int4 b4;
            b4.x = o4.x + (o4.x >= A1BASE ? D1OFF : D0OFF);
            b4.y = o4.y + (o4.y >= A1BASE ? D1OFF : D0OFF);
            b4.z = o4.z + (o4.z >= A1BASE ? D1OFF : D0OFF);
            b4.w = o4.w + (o4.w >= A1BASE ? D1OFF : D0OFF);

            const uint4 a0 = *(const uint4*)(vals + o4.x);
            const uint4 b0 = *(const uint4*)(vals + b4.x);
            const uint4 a1 = *(const uint4*)(vals + o4.y);
            const uint4 b1 = *(const uint4*)(vals + b4.y);
            const uint4 a2 = *(const uint4*)(vals + o4.z);
            const uint4 b2 = *(const uint4*)(vals + b4.z);
            const uint4 a3 = *(const uint4*)(vals + o4.w);
            const uint4 b3 = *(const uint4*)(vals + b4.w);
            fma_feat(accA, w0, a0);
            fma_feat(accB, w0, b0);
            fma_feat(accA, w1, a1);
            fma_feat(accB, w1, b1);
            fma_feat(accA, w2, a2);
            fma_feat(accB, w2, b2);
            fma_feat(accA, w3, a3);
            fma_feat(accB, w3, b3);
        }

        float sA[8], sB[8];
        #pragma unroll
        for (int j = 0; j < 4; ++j) {
            sA[2 * j + 0] = fast_sigmoid(__low2float(accA[j]));
            sA[2 * j + 1] = fast_sigmoid(__high2float(accA[j]));
            sB[2 * j + 0] = fast_sigmoid(__low2float(accB[j]));
            sB[2 * j + 1] = fast_sigmoid(__high2float(accB[j]));
        }

        if (l < NL - 1) {
            uint4 pA, pB;
            pA.x = pk16(sA[0], sA[1]); pA.y = pk16(sA[2], sA[3]);
            pA.z = pk16(sA[4], sA[5]); pA.w = pk16(sA[6], sA[7]);
            pB.x = pk16(sB[0], sB[1]); pB.y = pk16(sB[2], sB[3]);
            pB.z = pk16(sB[4], sB[5]); pB.w = pk16(sB[6], sB[7]);
            const int F = NIN + l * NW + t;
            *(uint4*)(vals + F * 16)          = pA;
            *(uint4*)(vals + D0OFF + F * 16)  = pB;
            if (l < 2) {                       // layers 0,1 feed the replica
                if (F < NREP) {
                    *(uint4*)(vals + A1BASE + F * 16) = pA;
                    *(uint4*)(vals + B1BASE + F * 16) = pB;
                }
            }
            __syncthreads();           // ONE barrier per 16 rows per layer
        } else {
            #pragma unroll
            for (int r = 0; r < 8; ++r) {
                out[(row0 + r) * NW + t]     = sA[r];
                out[(row0 + 8 + r) * NW + t] = sB[r];
            }
        }
    }
}

// R20 prepass, one block per layer (t = unit). Phase octet = units
// 8o..8o+7 (consecutive lanes; R14/R15-verified granularity).
// 1. each unit: packed histograms cnt[g], ch[g] (choosable = idx<NREP).
// 2. octet leader (t&7==0): D[g]=sum cnt, ring transport s[g] =
//    clamp(c + prefix(D-16), 0, CHtot[g]) with c chosen feasible-first;
//    allocate s[g] to units greedily -> take_u[g].
// 3. each unit: first take[g] choosable items of group g shift to copy1
//    (final group (g+1)&7); counting-sort by final group + spaced-2
//    rotation (R15-verified) -> idxb absolute A offsets.
__global__ __launch_bounds__(256)
void emit_kernel(const float* __restrict__ weights,
                 const int* __restrict__ edge_idx,
                 int* __restrict__ idxb,
                 unsigned* __restrict__ wpk)
{
    __shared__ u64 s_cnt[NW];
    __shared__ u64 s_ch[NW];
    __shared__ u64 s_take[NW];

    const int l = blockIdx.x;
    const int t = threadIdx.x;
    const int base = (l * NW + t) * NK;
    const int lane = t & 63;

    int   idxv[NK];
    float wv[NK];
    u64 cnt = 0, ch = 0;
    #pragma unroll
    for (int j = 0; j < NK; ++j) {
        idxv[j] = edge_idx[base + j];
        wv[j]   = weights[base + j];
        const int g = idxv[j] & 7;
        cnt += 1ull << (g * 8);
        if (idxv[j] < NREP) ch += 1ull << (g * 8);
    }
    s_cnt[t] = cnt;
    s_ch[t]  = ch;
    __syncthreads();

    if ((t & 7) == 0) {
        u64 chu[8], tku[8];
        u64 D = 0, CH = 0;
        #pragma unroll
        for (int r = 0; r < 8; ++r) {
            chu[r] = s_ch[t + r];
            D  += s_cnt[t + r];      // bytewise sums <=128, no carry
            CH += chu[r];
            tku[r] = 0;
        }
        int pg[8], CHg[8];
        int pfx = 0, minp = 0, chi = 0x7fffffff;
        #pragma unroll
        for (int g = 0; g < 8; ++g) {
            pfx += (int)((D >> (g * 8)) & 0xFF) - 16;
            pg[g] = pfx;
            if (pfx < minp) minp = pfx;
            CHg[g] = (int)((CH >> (g * 8)) & 0xFF);
            const int hi = CHg[g] - pfx;
            if (hi < chi) chi = hi;
        }
        int c = -minp; if (c < 0) c = 0;
        if (c > chi) c = (chi < 0) ? 0 : chi;   // best-effort when infeasible
        #pragma unroll
        for (int g = 0; g < 8; ++g) {
            int s = c + pg[g];
            s = s < 0 ? 0 : s;
            if (s > CHg[g]) s = CHg[g];
            int rem = s;
            #pragma unroll
            for (int r = 0; r < 8; ++r) {
                const int av = (int)((chu[r] >> (g * 8)) & 0xFF);
                const int tk = rem < av ? rem : av;
                rem -= tk;
                tku[r] += (u64)tk << (g * 8);
            }
        }
        #pragma unroll
        for (int r = 0; r < 8; ++r) s_take[t + r] = tku[r];
    }
    __syncthreads();
    const u64 take = s_take[t];

    // per-item shift decision: first take[g] choosable items of group g
    u64 usedc = 0;
    int fg[NK], sh[NK];
    #pragma unroll
    for (int j = 0; j < NK; ++j) {
        const int g = idxv[j] & 7;
        int s_ = 0;
        if (idxv[j] < NREP) {
            const int uc = (int)((usedc >> (g * 8)) & 0xFF);
            const int tk = (int)((take  >> (g * 8)) & 0xFF);
            s_ = (uc < tk) ? 1 : 0;
            usedc += 1ull << (g * 8);
        }
        sh[j] = s_;
        fg[j] = (g + s_) & 7;
    }

    // counting sort by final group + spaced-2 rotation (R15-verified)
    u64 fcnt = 0;
    #pragma unroll
    for (int j = 0; j < NK; ++j)
        fcnt += 1ull << (fg[j] * 8);

    u64 x = fcnt;
    x += x << 8;
    x += x << 16;
    x += x << 32;
    u64 cur = x << 8;             // exclusive prefix

    const int rot = (2 * (lane & 7) + ((lane >> 3) & 7)) & 15;
    #pragma unroll
    for (int j = 0; j < NK; ++j) {
        const int g   = fg[j];
        const int pos = (int)((cur >> (g * 8)) & 0xFF);   // unique 0..15
        cur += 1ull << (g * 8);
        const int slot = (pos + rot) & 15;
        idxb[base + slot] = sh[j] ? (A1BASE + (idxv[j] << 4))
                                  : (idxv[j] << 4);
        wpk [base + slot] = pk16(wv[j], wv[j]);
    }
}

extern "C" void kernel_launch(void* const* d_in, const int* in_sizes, int n_in,
                              void* d_out, int out_size, void* d_ws, size_t ws_size,
                              hipStream_t stream)
{
    const float* inputs   = (const float*)d_in[0];
    const float* weights  = (const float*)d_in[1];
    const float* biases   = (const float*)d_in[2];
    const int*   edge_idx = (const int*)d_in[3];
    float* out = (float*)d_out;

    dim3 grid(NB / RPB);   // 2048
    dim3 block(NW);        // 256

    const size_t need = (size_t)NPARAM * 4 * 2;     // 256 KB
    if (ws_size >= need) {
        int*      idxb = (int*)d_ws;
        unsigned* wpk  = (unsigned*)((char*)d_ws + (size_t)NPARAM * 4);
        emit_kernel<<<NL, NW, 0, stream>>>(weights, edge_idx, idxb, wpk);
        ffn_gather_kernel<true><<<grid, block, 0, stream>>>(
            inputs, weights, biases, edge_idx, idxb, wpk, out);
    } else {
        ffn_gather_kernel<false><<<grid, block, 0, stream>>>(
            inputs, weights, biases, edge_idx, nullptr, nullptr, out);
    }
}

// Round 8
// 134.243 us; speedup vs baseline: 1.0929x; 1.0929x over previous
//
#include <hip/hip_runtime.h>
#include <hip/hip_bf16.h>
#include <hip/hip_fp16.h>

// Sparse gather-FFN, DS-pipe bound. FINAL (R21 = revert to R15, the
// measured optimum). Verified model: per CU, 8192 wave ds_read_b128
// (count invariant at f16/16B/8-rows-per-read) x 12cyc issue (m134
// ceiling) = 41us + conflict residual ~7.1cyc/instr = 24us + ~2us tail
// = 67us main, measured 67.0-67.2 (R2 bench).
// Conflict-floor evidence (six manipulations): R15 sort idx&7 + spaced-2
// rotation 1.494e7 (best); R14 coarse rot 2.20e7 (phase = 8 consecutive
// lanes, order matters); R16 per-lane +1 replica 1.334e7 (-11% only);
// R17 octet unit-permutation NULL; R18 idx&15 sort key EXACTLY ZERO
// delta (32-bank model confirmed); R20 octet-coordinated replication
// NULL (1.486e7) and +11us overhead. Residual 6.4-7.1 cyc/instr is an
// ordering-independent demand-variance floor; the only untried variant
// (full replica @ RPB=16) needs 123KB LDS -> 1 block/CU, costing more
// in occupancy than the ~2.7us it could save.
// Also refuted: VMEM gather offload (R18: L1 16B gathers 2.5-3x slower
// per instr than DS, main 73.2); RPB=8 shell (R16: +18us block overhead).
// Ceiling change requires fp8 row-packing (precision-infeasible: absmax
// already 0.0039 at f16) or more LDS per CU (hardware).

#define NB   32768
#define NIN  128
#define NL   8
#define NW   256
#define NK   16
#define RPB  16                       // rows per block = 2 octets x 8
#define STORED (NIN + (NL - 1) * NW)  // 1920 features per group
#define NPARAM (NL * NW * NK)         // 32768 (l,u,k) entries

typedef __fp16 fp16v2 __attribute__((ext_vector_type(2)));
typedef unsigned long long u64;

__device__ __forceinline__ unsigned pk16(float a, float b) {
    fp16v2 p = __builtin_amdgcn_cvt_pkrtz(a, b);   // v_cvt_pkrtz_f16_f32
    return __builtin_bit_cast(unsigned, p);
}

__device__ __forceinline__ __half2 as_h2(unsigned u) {
    return __builtin_bit_cast(__half2, u);
}

__device__ __forceinline__ float fast_sigmoid(float x) {
    return __builtin_amdgcn_rcpf(1.0f + __expf(-x));
}

// 8 row-MACs from one 16B packed-f16 word: 4x v_pk_fma_f16
__device__ __forceinline__ void fma_feat(__half2 acc[4], __half2 w2, uint4 p) {
    acc[0] = __hfma2(as_h2(p.x), w2, acc[0]);
    acc[1] = __hfma2(as_h2(p.y), w2, acc[1]);
    acc[2] = __hfma2(as_h2(p.z), w2, acc[2]);
    acc[3] = __hfma2(as_h2(p.w), w2, acc[3]);
}

template <bool PRE>
__global__ __launch_bounds__(256, 2)
void ffn_gather_kernel(const float* __restrict__ inputs,
                       const float* __restrict__ weights,
                       const float* __restrict__ biases,
                       const int*   __restrict__ edge_idx,
                       const int*   __restrict__ idxb,   // pre-scaled byte offs
                       const unsigned* __restrict__ wpk, // packed (w,w) f16
                       float* __restrict__ out)
{
    __shared__ uint4 valsA[STORED];   // group A: rows row0..row0+7
    __shared__ uint4 valsB[STORED];   // group B: rows row0+8..row0+15

    const int t = threadIdx.x;                       // 0..255, unit id
    const long long row0 = (long long)blockIdx.x * RPB;
    const char* vbaseA = (const char*)valsA;
    const char* vbaseB = (const char*)valsB;

    // ---- stage 128 input features x 16 rows: t<128 -> A, t>=128 -> B ----
    {
        const int f = t & 127;
        const long long r0 = row0 + ((t >> 7) << 3);   // +0 (A) or +8 (B)
        float v[8];
        #pragma unroll
        for (int r = 0; r < 8; ++r) v[r] = inputs[(r0 + r) * NIN + f];
        uint4 p;
        p.x = pk16(v[0], v[1]);
        p.y = pk16(v[2], v[3]);
        p.z = pk16(v[4], v[5]);
        p.w = pk16(v[6], v[7]);
        if (t < NIN) valsA[f] = p; else valsB[f] = p;
    }
    __syncthreads();

    // ---- layers ----
    #pragma unroll
    for (int l = 0; l < NL; ++l) {
        const int base = (l * NW + t) * NK;

        const float b = biases[l * NW + t];
        __half2 accA[4], accB[4];
        const __half2 bb = __float2half2_rn(b);
        #pragma unroll
        for (int j = 0; j < 4; ++j) { accA[j] = bb; accB[j] = bb; }

        #pragma unroll
        for (int kk = 0; kk < NK / 4; ++kk) {
            int4 o4;          // byte offsets into vals (shared by A and B!)
            __half2 w0, w1, w2, w3;
            if (PRE) {
                o4 = ((const int4*)(idxb + base))[kk];
                uint4 wp = ((const uint4*)(wpk + base))[kk];
                w0 = as_h2(wp.x); w1 = as_h2(wp.y);
                w2 = as_h2(wp.z); w3 = as_h2(wp.w);
            } else {
                int4 i4 = ((const int4*)(edge_idx + base))[kk];
                o4.x = i4.x << 4; o4.y = i4.y << 4;
                o4.z = i4.z << 4; o4.w = i4.w << 4;
                float4 w4 = ((const float4*)(weights + base))[kk];
                w0 = __float2half2_rn(w4.x);
                w1 = __float2half2_rn(w4.y);
                w2 = __float2half2_rn(w4.z);
                w3 = __float2half2_rn(w4.w);
            }
            // 8 independent gathers (two per feature, groups A+B)
            const uint4 a0 = *(const uint4*)(vbaseA + o4.x);
            const uint4 b0 = *(const uint4*)(vbaseB + o4.x);
            const uint4 a1 = *(const uint4*)(vbaseA + o4.y);
            const uint4 b1 = *(const uint4*)(vbaseB + o4.y);
            const uint4 a2 = *(const uint4*)(vbaseA + o4.z);
            const uint4 b2 = *(const uint4*)(vbaseB + o4.z);
            const uint4 a3 = *(const uint4*)(vbaseA + o4.w);
            const uint4 b3 = *(const uint4*)(vbaseB + o4.w);
            fma_feat(accA, w0, a0);
            fma_feat(accB, w0, b0);
            fma_feat(accA, w1, a1);
            fma_feat(accB, w1, b1);
            fma_feat(accA, w2, a2);
            fma_feat(accB, w2, b2);
            fma_feat(accA, w3, a3);
            fma_feat(accB, w3, b3);
        }

        float sA[8], sB[8];
        #pragma unroll
        for (int j = 0; j < 4; ++j) {
            sA[2 * j + 0] = fast_sigmoid(__low2float(accA[j]));
            sA[2 * j + 1] = fast_sigmoid(__high2float(accA[j]));
            sB[2 * j + 0] = fast_sigmoid(__low2float(accB[j]));
            sB[2 * j + 1] = fast_sigmoid(__high2float(accB[j]));
        }

        if (l < NL - 1) {
            uint4 pA, pB;
            pA.x = pk16(sA[0], sA[1]); pA.y = pk16(sA[2], sA[3]);
            pA.z = pk16(sA[4], sA[5]); pA.w = pk16(sA[6], sA[7]);
            pB.x = pk16(sB[0], sB[1]); pB.y = pk16(sB[2], sB[3]);
            pB.z = pk16(sB[4], sB[5]); pB.w = pk16(sB[6], sB[7]);
            valsA[NIN + l * NW + t] = pA;
            valsB[NIN + l * NW + t] = pB;
            __syncthreads();           // ONE barrier per 16 rows per layer
        } else {
            #pragma unroll
            for (int r = 0; r < 8; ++r) {
                out[(row0 + r) * NW + t]     = sA[r];
                out[(row0 + 8 + r) * NW + t] = sB[r];
            }
        }
    }
}

// R15 prepass (verified best): byte-offset indices + packed (w,w) f16
// weights, k-slots counting-sorted by bank group (idx & 7) with the
// spaced-2 per-lane rotation. Within any 8 consecutive lanes (one
// ds_read_b128 phase), rotations are 8 distinct positions spaced 2
// apart -> ~8 distinct bank groups under the sorted position->group map.
__global__ __launch_bounds__(256)
void balance_prepass_kernel(const float* __restrict__ weights,
                            const int* __restrict__ edge_idx,
                            int* __restrict__ idxb,
                            unsigned* __restrict__ wpk)
{
    const int t = blockIdx.x * 256 + threadIdx.x;   // 0..2047: unit (l*NW+u)
    const int lane = t & 63;                        // main-kernel wave lane
    const int base = t * NK;

    int   idxv[NK];
    float wv[NK];
    #pragma unroll
    for (int j = 0; j < NK; ++j) {
        idxv[j] = edge_idx[base + j];
        wv[j]   = weights[base + j];
    }

    // counting sort by bank group, 8x8-bit packed counters
    u64 cntp = 0;
    #pragma unroll
    for (int j = 0; j < NK; ++j)
        cntp += 1ull << ((idxv[j] & 7) * 8);

    // per-byte inclusive prefix sum, then shift up one byte -> exclusive
    u64 x = cntp;
    x += x << 8;
    x += x << 16;
    x += x << 32;
    u64 cur = x << 8;     // cur byte g = #items with group < g

    const int rot = (2 * (lane & 7) + ((lane >> 3) & 7)) & 15;
    #pragma unroll
    for (int j = 0; j < NK; ++j) {
        const int g   = idxv[j] & 7;
        const int pos = (int)((cur >> (g * 8)) & 0xFF);  // unique 0..15
        cur += 1ull << (g * 8);
        const int slot = (pos + rot) & 15;
        idxb[base + slot] = idxv[j] << 4;
        wpk [base + slot] = pk16(wv[j], wv[j]);
    }
}

extern "C" void kernel_launch(void* const* d_in, const int* in_sizes, int n_in,
                              void* d_out, int out_size, void* d_ws, size_t ws_size,
                              hipStream_t stream)
{
    const float* inputs   = (const float*)d_in[0];
    const float* weights  = (const float*)d_in[1];
    const float* biases   = (const float*)d_in[2];
    const int*   edge_idx = (const int*)d_in[3];
    float* out = (float*)d_out;

    dim3 grid(NB / RPB);   // 2048
    dim3 block(NW);        // 256

    const size_t need = (size_t)NPARAM * 4 * 2;     // 256 KB
    if (ws_size >= need) {
        int*      idxb = (int*)d_ws;
        unsigned* wpk  = (unsigned*)((char*)d_ws + (size_t)NPARAM * 4);
        balance_prepass_kernel<<<NL * NW / 256, 256, 0, stream>>>(
            weights, edge_idx, idxb, wpk);
        ffn_gather_kernel<true><<<grid, block, 0, stream>>>(
            inputs, weights, biases, edge_idx, idxb, wpk, out);
    } else {
        ffn_gather_kernel<false><<<grid, block, 0, stream>>>(
            inputs, weights, biases, edge_idx, nullptr, nullptr, out);
    }
}